// Round 6
// baseline (231.110 us; speedup 1.0000x reference)
//
#include <hip/hip_runtime.h>
#include <hip/hip_bf16.h>
#include <math.h>

#define HDIM 512
#define LSEQ 1024
#define BSZ  4

typedef __attribute__((ext_vector_type(8))) short short8;
typedef __attribute__((ext_vector_type(4))) float floatx4;

__device__ __forceinline__ float2 cmul(float2 a, float2 b) {
  float2 r;
  r.x = a.x * b.x - a.y * b.y;
  r.y = a.x * b.y + a.y * b.x;
  return r;
}
__device__ __forceinline__ float2 cadd(float2 a, float2 b) {
  float2 r; r.x = a.x + b.x; r.y = a.y + b.y; return r;
}
__device__ __forceinline__ float2 cfma(float2 a, float2 b, float2 c) {
  c.x += a.x * b.x - a.y * b.y;
  c.y += a.x * b.y + a.y * b.x;
  return c;
}
__device__ __forceinline__ ushort f2bf(float f) {
  __hip_bfloat16 h = __float2bfloat16(f);
  return *(ushort*)&h;
}

// ---------------- LayerNorm: one wave per (b,t) row ----------------
__global__ __launch_bounds__(64) void ln_kernel(const float* __restrict__ x,
    const float* __restrict__ w, const float* __restrict__ b, float* __restrict__ xn) {
  int row = blockIdx.x;           // b*L + t   (4096 rows)
  int lane = threadIdx.x;
  const float* xr = x + (size_t)row * HDIM;
  float4 v0 = ((const float4*)xr)[lane];
  float4 v1 = ((const float4*)xr)[lane + 64];
  float s  = v0.x + v0.y + v0.z + v0.w + v1.x + v1.y + v1.z + v1.w;
  float ss = v0.x*v0.x + v0.y*v0.y + v0.z*v0.z + v0.w*v0.w
           + v1.x*v1.x + v1.y*v1.y + v1.z*v1.z + v1.w*v1.w;
  #pragma unroll
  for (int m = 1; m < 64; m <<= 1) { s += __shfl_xor(s, m); ss += __shfl_xor(ss, m); }
  float mu   = s * (1.0f / HDIM);
  float var  = ss * (1.0f / HDIM) - mu * mu;
  float rstd = rsqrtf(var + 1e-5f);
  float4 w0 = ((const float4*)w)[lane];
  float4 w1 = ((const float4*)w)[lane + 64];
  float4 b0 = ((const float4*)b)[lane];
  float4 b1 = ((const float4*)b)[lane + 64];
  float4 o0, o1;
  o0.x = (v0.x - mu) * rstd * w0.x + b0.x;
  o0.y = (v0.y - mu) * rstd * w0.y + b0.y;
  o0.z = (v0.z - mu) * rstd * w0.z + b0.z;
  o0.w = (v0.w - mu) * rstd * w0.w + b0.w;
  o1.x = (v1.x - mu) * rstd * w1.x + b1.x;
  o1.y = (v1.y - mu) * rstd * w1.y + b1.y;
  o1.z = (v1.z - mu) * rstd * w1.z + b1.z;
  o1.w = (v1.w - mu) * rstd * w1.w + b1.w;
  float* xo = xn + (size_t)row * HDIM;
  ((float4*)xo)[lane] = o0;
  ((float4*)xo)[lane + 64] = o1;
}

// ---------------- K generation (register-resident DPLR column chains) ----------------
// K[32a+b] = Re( (c^T (Ab^32)^a) . (Ab^b Bb) )
__global__ __launch_bounds__(512) void kgen_kernel(
    const float* __restrict__ lre, const float* __restrict__ lim,
    const float* __restrict__ pre, const float* __restrict__ pim,
    const float* __restrict__ bre, const float* __restrict__ bim,
    const float* __restrict__ cre, const float* __restrict__ cim,
    const float* __restrict__ logstep, float* __restrict__ Kout) {
  __shared__ float2 Ldab[64], Lu[64], Lr[64], LBb[64];
  __shared__ float2 P[8][64];     // partial dots
  __shared__ float2 M32[4096];    // Ab^32 row-major [i][j]
  __shared__ float2 Rv[2048];     // [a*64+n] = (c^T (Ab^32)^a)[n]
  __shared__ float2 Wv[2048];     // [n*32+b] = (Ab^b Bb)[n]
  int tid = threadIdx.x;
  int j = tid & 63;       // column (phase B) / output index m (phase C)
  int p = tid >> 6;       // partial group: rows p*8..p*8+7

  // --- Phase A: DPLR setup (wave 0, lane n = mode n) ---
  if (tid < 64) {
    int n = tid;
    float step = expf(logstep[0]);
    float g = 2.0f / step;
    float lr = lre[n], li = lim[n];
    float pr = pre[n], pi = pim[n];
    float br = bre[n], bi = bim[n];
    float den  = (g - lr) * (g - lr) + li * li;
    float dinr = (g - lr) / den, dini = li / den;
    float dabr = (g + lr) * dinr - li * dini;
    float dabi = (g + lr) * dini + li * dinr;
    float ur = dinr * pr - dini * pi;
    float ui = dinr * pi + dini * pr;
    float qr = pr * dinr + pi * dini;
    float qi = pr * dini - pi * dinr;
    float pm2 = pr * pr + pi * pi;
    float betr = pm2 * dinr, beti = pm2 * dini;
    float gar = qr * br - qi * bi;
    float gai = qr * bi + qi * br;
    #pragma unroll
    for (int m = 1; m < 64; m <<= 1) {
      betr += __shfl_xor(betr, m); beti += __shfl_xor(beti, m);
      gar  += __shfl_xor(gar, m);  gai  += __shfl_xor(gai, m);
    }
    float obr = 1.0f + betr, obi = beti;
    float ob2 = obr * obr + obi * obi;
    float kr = -2.0f * g * obr / ob2;
    float ki =  2.0f * g * obi / ob2;
    float rr = kr * qr - ki * qi;
    float ri = kr * qi + ki * qr;
    float tgr = (gar * obr + gai * obi) / ob2;
    float tgi = (gai * obr - gar * obi) / ob2;
    float dbr = dinr * br - dini * bi;
    float dbi = dinr * bi + dini * br;
    float Bbr = 2.0f * (dbr - (ur * tgr - ui * tgi));
    float Bbi = 2.0f * (dbi - (ur * tgi + ui * tgr));
    float2 t;
    t.x = dabr; t.y = dabi; Ldab[n] = t;
    t.x = ur;   t.y = ui;   Lu[n]   = t;
    t.x = rr;   t.y = ri;   Lr[n]   = t;
    t.x = Bbr;  t.y = Bbi;  LBb[n]  = t;
  }
  __syncthreads();

  // --- Phase B: 64 column chains, 32 applications of Ab (DPLR form) ---
  float2 dab[8], u[8], rn[8], cv[8];
  #pragma unroll
  for (int ii = 0; ii < 8; ii++) {
    int n = p * 8 + ii;
    dab[ii] = Ldab[n]; u[ii] = Lu[n]; rn[ii] = Lr[n];
  }
  float2 rj = Lr[j];
  #pragma unroll
  for (int ii = 0; ii < 8; ii++) {
    int n = p * 8 + ii;
    cv[ii] = cmul(u[ii], rj);
    if (n == j) cv[ii] = cadd(cv[ii], dab[ii]);
  }
  for (int s = 0; s < 31; s++) {
    float2 part; part.x = 0.f; part.y = 0.f;
    #pragma unroll
    for (int ii = 0; ii < 8; ii++) part = cfma(rn[ii], cv[ii], part);
    P[p][j] = part;
    __syncthreads();
    float2 d; d.x = 0.f; d.y = 0.f;
    #pragma unroll
    for (int q = 0; q < 8; q++) d = cadd(d, P[q][j]);
    __syncthreads();
    #pragma unroll
    for (int ii = 0; ii < 8; ii++) {
      float2 nc = cmul(dab[ii], cv[ii]);
      nc = cfma(u[ii], d, nc);
      cv[ii] = nc;
    }
  }
  #pragma unroll
  for (int ii = 0; ii < 8; ii++) M32[(p * 8 + ii) * 64 + j] = cv[ii];
  if (tid < 64) { float2 cc; cc.x = cre[tid]; cc.y = cim[tid]; Rv[tid] = cc; }
  __syncthreads();

  // --- Phase C: R chain, parallel partials with register M-strip ---
  float2 Mreg[8];
  #pragma unroll
  for (int ii = 0; ii < 8; ii++) Mreg[ii] = M32[(p * 8 + ii) * 64 + j];
  for (int a = 1; a < 32; a++) {
    float2 part; part.x = 0.f; part.y = 0.f;
    #pragma unroll
    for (int ii = 0; ii < 8; ii++) {
      float2 Rk = Rv[(a - 1) * 64 + p * 8 + ii];
      part = cfma(Rk, Mreg[ii], part);
    }
    P[p][j] = part;
    __syncthreads();
    if (p == 0) {
      float2 d; d.x = 0.f; d.y = 0.f;
      #pragma unroll
      for (int q = 0; q < 8; q++) d = cadd(d, P[q][j]);
      Rv[a * 64 + j] = d;
    }
    __syncthreads();
  }

  // --- Phase D: W chain (wave 0) ---
  if (tid < 64) {
    int n = tid;
    float2 dab0 = Ldab[n], u0 = Lu[n], r0 = Lr[n];
    float2 w = LBb[n];
    Wv[n * 32 + 0] = w;
    for (int b = 1; b < 32; b++) {
      float dr = r0.x * w.x - r0.y * w.y;
      float di = r0.x * w.y + r0.y * w.x;
      #pragma unroll
      for (int m = 1; m < 64; m <<= 1) { dr += __shfl_xor(dr, m); di += __shfl_xor(di, m); }
      float2 nw;
      nw.x = dab0.x * w.x - dab0.y * w.y + u0.x * dr - u0.y * di;
      nw.y = dab0.x * w.y + dab0.y * w.x + u0.x * di + u0.y * dr;
      w = nw;
      Wv[n * 32 + b] = w;
    }
  }
  __syncthreads();

  // --- Phase E: K[32a+b] = Re(R_a . W_b) ---
  #pragma unroll
  for (int q = 0; q < 2; q++) {
    int midx = q * 512 + tid;
    int a = midx >> 5, b = midx & 31;
    float acc = 0.f;
    for (int n = 0; n < 64; n++) {
      float2 R = Rv[a * 64 + n];
      float2 W = Wv[n * 32 + b];
      acc += R.x * W.x - R.y * W.y;
    }
    Kout[midx] = acc;
  }
}

// ---------------- Prep: transpose(xn->U) + wconv + toeplitz, one launch ----------------
// blocks [0,512): transpose; [512,768): weight convert; [768,1280): toeplitz.
__global__ __launch_bounds__(256) void prep_kernel(
    const float* __restrict__ xn, const float* __restrict__ K,
    const float* __restrict__ w1, const float* __restrict__ w2,
    ushort* __restrict__ Uhi, ushort* __restrict__ Ulo,
    ushort* __restrict__ Thi, ushort* __restrict__ Tlo,
    ushort* __restrict__ Wst) {
  __shared__ float tile[64][65];
  int blk = blockIdx.x;
  int tid = threadIdx.x;
  if (blk < 512) {
    // --- transpose xn [B,L,H] -> U[c=b*512+h][t] hi/lo bf16 ---
    int ht = blk & 7, lt = (blk >> 3) & 15, b = blk >> 7;
    #pragma unroll
    for (int q = 0; q < 16; q++) {
      int idx = q * 256 + tid;
      int r = idx >> 6, c = idx & 63;               // r: l-offset, c: h-offset
      tile[r][c] = xn[((size_t)(b * LSEQ + lt * 64 + r)) * HDIM + ht * 64 + c];
    }
    __syncthreads();
    #pragma unroll
    for (int q = 0; q < 16; q++) {
      int idx = q * 256 + tid;
      int r = idx >> 6, c = idx & 63;               // r: h-offset, c: l-offset
      float v = tile[c][r];
      ushort h = f2bf(v);
      float rem = v - __bfloat162float(*(__hip_bfloat16*)&h);
      ushort l = f2bf(rem);
      size_t off = ((size_t)(b * HDIM + ht * 64 + r)) * LSEQ + lt * 64 + c;
      Uhi[off] = h;
      Ulo[off] = l;
    }
  } else if (blk < 768) {
    // --- weight convert: Wst[n][k], n<512 from w1, else w2 ---
    int e0 = ((blk - 512) * 256 + tid) * 8;         // 524288 total
    int n = e0 >> 9, k0 = e0 & 511;
    const float* Wr = (n < 512) ? (w1 + (size_t)n * 512 + k0)
                                : (w2 + (size_t)(n - 512) * 512 + k0);
    ushort tmp[8];
    #pragma unroll
    for (int t = 0; t < 8; t++) tmp[t] = f2bf(Wr[t]);
    *(short8*)&Wst[e0] = *(short8*)tmp;
  } else {
    // --- toeplitz: T[t][tau] = K[t-tau], hi/lo bf16 ---
    int r = blk - 768;                              // 0..511
    int t = r * 2 + (tid >> 7);
    int tau0 = (tid & 127) * 8;
    ushort hi[8], lo[8];
    #pragma unroll
    for (int q = 0; q < 8; q++) {
      int tau = tau0 + q;
      float v = (tau <= t) ? K[t - tau] : 0.f;
      hi[q] = f2bf(v);
      float rem = v - __bfloat162float(*(__hip_bfloat16*)&hi[q]);
      lo[q] = f2bf(rem);
    }
    *(short8*)&Thi[(size_t)t * 1024 + tau0] = *(short8*)hi;
    *(short8*)&Tlo[(size_t)t * 1024 + tau0] = *(short8*)lo;
  }
}

// -------- Conv GEMM (barrier-free, direct-global frags) + fused GELU epilogue --------
// Y = Thi*Uhi^T + Tlo*Uhi^T + Thi*Ulo^T; A[b,t,h] = bf16(gelu(Y + d*xn))
__global__ __launch_bounds__(256) void conv_gemm_kernel(
    const ushort* __restrict__ Thi, const ushort* __restrict__ Tlo,
    const ushort* __restrict__ Uhi, const ushort* __restrict__ Ulo,
    const float* __restrict__ xn, const float* __restrict__ dptr,
    __hip_bfloat16* __restrict__ A) {
  int tid = threadIdx.x;
  int lane = tid & 63;
  int wv = tid >> 6;
  int wm = wv >> 1, wn = wv & 1;
  int bm = blockIdx.y, bn = blockIdx.x;   // bm<16 (t tiles), bn<32 (c tiles)
  int fr = lane & 15, fq = (lane >> 4) * 8;
  floatx4 acc[2][2] = {};
  size_t arow = (size_t)(bm * 64 + wm * 32 + fr) * 1024 + fq;
  size_t brow = (size_t)(bn * 64 + wn * 32 + fr) * 1024 + fq;
  #pragma unroll 2
  for (int k0 = 0; k0 < 1024; k0 += 32) {
    short8 ah[2], al[2], bh[2], bl[2];
    #pragma unroll
    for (int i = 0; i < 2; i++) {
      ah[i] = *(const short8*)&Thi[arow + (size_t)(i * 16) * 1024 + k0];
      al[i] = *(const short8*)&Tlo[arow + (size_t)(i * 16) * 1024 + k0];
      bh[i] = *(const short8*)&Uhi[brow + (size_t)(i * 16) * 1024 + k0];
      bl[i] = *(const short8*)&Ulo[brow + (size_t)(i * 16) * 1024 + k0];
    }
    #pragma unroll
    for (int i = 0; i < 2; i++)
      #pragma unroll
      for (int j = 0; j < 2; j++) {
        acc[i][j] = __builtin_amdgcn_mfma_f32_16x16x32_bf16(ah[i], bh[j], acc[i][j], 0, 0, 0);
        acc[i][j] = __builtin_amdgcn_mfma_f32_16x16x32_bf16(al[i], bh[j], acc[i][j], 0, 0, 0);
        acc[i][j] = __builtin_amdgcn_mfma_f32_16x16x32_bf16(ah[i], bl[j], acc[i][j], 0, 0, 0);
      }
  }
  float d = dptr[0];
  int row0 = bm * 64 + wm * 32;
  int col0 = bn * 64 + wn * 32;
  int fc = lane & 15, frq = (lane >> 4) * 4;
  #pragma unroll
  for (int i = 0; i < 2; i++)
    #pragma unroll
    for (int j = 0; j < 2; j++)
      #pragma unroll
      for (int r = 0; r < 4; r++) {
        int t = row0 + i * 16 + frq + r;
        int c = col0 + j * 16 + fc;
        int b = c >> 9, h = c & 511;
        size_t off = (size_t)(b * LSEQ + t) * HDIM + h;
        float y = acc[i][j][r] + d * xn[off];
        float tnh = tanhf(0.7978845608028654f * (y + 0.044715f * y * y * y));
        A[off] = __float2bfloat16(0.5f * y * (1.0f + tnh));
      }
}

// ---- Proj GEMM (barrier-free): C1/C2 dual tile + fused sigmoid-gate epilogue ----
// out[bt,n] = x[bt,n] + (A.W1^T + ob)[bt,n] * sigmoid((A.W2^T + o2b)[bt,n])
__global__ __launch_bounds__(256) void proj_kernel(
    const __hip_bfloat16* __restrict__ Abuf, const ushort* __restrict__ Wst,
    const float* __restrict__ x, const float* __restrict__ ob,
    const float* __restrict__ o2b, float* __restrict__ out) {
  int tid = threadIdx.x;
  int lane = tid & 63;
  int wv = tid >> 6;
  int wm = wv >> 1, wn = wv & 1;
  int bm = blockIdx.y, bn = blockIdx.x;   // bm<64 (bt tiles), bn<8 (n tiles)
  int fr = lane & 15, fq = (lane >> 4) * 8;
  floatx4 acc1[2][2] = {}, acc2[2][2] = {};
  const ushort* Ab = (const ushort*)Abuf;
  size_t arow = (size_t)(bm * 64 + wm * 32 + fr) * 512 + fq;
  size_t w1row = (size_t)(bn * 64 + wn * 32 + fr) * 512 + fq;
  size_t w2row = w1row + (size_t)512 * 512;
  #pragma unroll 2
  for (int k0 = 0; k0 < 512; k0 += 32) {
    short8 af[2], b1[2], b2[2];
    #pragma unroll
    for (int i = 0; i < 2; i++) {
      af[i] = *(const short8*)&Ab[arow + (size_t)(i * 16) * 512 + k0];
      b1[i] = *(const short8*)&Wst[w1row + (size_t)(i * 16) * 512 + k0];
      b2[i] = *(const short8*)&Wst[w2row + (size_t)(i * 16) * 512 + k0];
    }
    #pragma unroll
    for (int i = 0; i < 2; i++)
      #pragma unroll
      for (int j = 0; j < 2; j++) {
        acc1[i][j] = __builtin_amdgcn_mfma_f32_16x16x32_bf16(af[i], b1[j], acc1[i][j], 0, 0, 0);
        acc2[i][j] = __builtin_amdgcn_mfma_f32_16x16x32_bf16(af[i], b2[j], acc2[i][j], 0, 0, 0);
      }
  }
  int row0 = bm * 64 + wm * 32;
  int col0 = bn * 64 + wn * 32;
  int fc = lane & 15, frq = (lane >> 4) * 4;
  #pragma unroll
  for (int i = 0; i < 2; i++)
    #pragma unroll
    for (int j = 0; j < 2; j++)
      #pragma unroll
      for (int r = 0; r < 4; r++) {
        int row = row0 + i * 16 + frq + r;      // bt
        int col = col0 + j * 16 + fc;           // n in [0,512)
        float c1 = acc1[i][j][r] + ob[col];
        float c2 = acc2[i][j][r] + o2b[col];
        float gate = 1.0f / (1.0f + expf(-c2));
        size_t off = (size_t)row * HDIM + col;
        out[off] = x[off] + c1 * gate;
      }
}

extern "C" void kernel_launch(void* const* d_in, const int* in_sizes, int n_in,
                              void* d_out, int out_size, void* d_ws, size_t ws_size,
                              hipStream_t stream) {
  const float* x   = (const float*)d_in[0];
  const float* nw  = (const float*)d_in[1];
  const float* nb  = (const float*)d_in[2];
  const float* lre = (const float*)d_in[3];
  const float* lim = (const float*)d_in[4];
  const float* pre = (const float*)d_in[5];
  const float* pim = (const float*)d_in[6];
  const float* bre = (const float*)d_in[7];
  const float* bim = (const float*)d_in[8];
  const float* cre = (const float*)d_in[9];
  const float* cim = (const float*)d_in[10];
  const float* dsc = (const float*)d_in[11];
  const float* lst = (const float*)d_in[12];
  const float* w1  = (const float*)d_in[13];
  const float* ob  = (const float*)d_in[14];
  const float* w2  = (const float*)d_in[15];
  const float* o2b = (const float*)d_in[16];

  char* ws = (char*)d_ws;
  // Workspace layout (26 MB used, no aliasing):
  float* xn    = (float*)(ws);                          // 0..8MB
  ushort* Uhi  = (ushort*)(ws + (size_t)(8  << 20));    // 8..12MB
  ushort* Ulo  = (ushort*)(ws + (size_t)(12 << 20));    // 12..16MB
  ushort* Thi  = (ushort*)(ws + (size_t)(16 << 20));    // 16..18MB
  ushort* Tlo  = (ushort*)(ws + (size_t)(18 << 20));    // 18..20MB
  ushort* Wst  = (ushort*)(ws + (size_t)(20 << 20));    // 20..21MB
  __hip_bfloat16* Abuf = (__hip_bfloat16*)(ws + (size_t)(21 << 20)); // 21..25MB
  float* Kbuf  = (float*)(ws + (size_t)(25 << 20));     // 4KB
  float* out   = (float*)d_out;

  ln_kernel<<<dim3(4096), dim3(64), 0, stream>>>(x, nw, nb, xn);
  kgen_kernel<<<dim3(1), dim3(512), 0, stream>>>(lre, lim, pre, pim, bre, bim,
                                                 cre, cim, lst, Kbuf);
  prep_kernel<<<dim3(1280), dim3(256), 0, stream>>>(xn, Kbuf, w1, w2,
                                                    Uhi, Ulo, Thi, Tlo, Wst);
  conv_gemm_kernel<<<dim3(32, 16), dim3(256), 0, stream>>>(Thi, Tlo, Uhi, Ulo,
                                                           xn, dsc, Abuf);
  proj_kernel<<<dim3(8, 64), dim3(256), 0, stream>>>(Abuf, Wst, x, ob, o2b, out);
}

// Round 7
// 183.558 us; speedup vs baseline: 1.2591x; 1.2591x over previous
//
#include <hip/hip_runtime.h>
#include <hip/hip_bf16.h>
#include <math.h>

#define HDIM 512
#define LSEQ 1024
#define BSZ  4

typedef __attribute__((ext_vector_type(8))) short short8;
typedef __attribute__((ext_vector_type(4))) float floatx4;

__device__ __forceinline__ float2 cmul(float2 a, float2 b) {
  float2 r;
  r.x = a.x * b.x - a.y * b.y;
  r.y = a.x * b.y + a.y * b.x;
  return r;
}
__device__ __forceinline__ float2 cadd(float2 a, float2 b) {
  float2 r; r.x = a.x + b.x; r.y = a.y + b.y; return r;
}
__device__ __forceinline__ float2 cfma(float2 a, float2 b, float2 c) {
  c.x += a.x * b.x - a.y * b.y;
  c.y += a.x * b.y + a.y * b.x;
  return c;
}
__device__ __forceinline__ ushort f2bf(float f) {
  __hip_bfloat16 h = __float2bfloat16(f);
  return *(ushort*)&h;
}

// ---------------- LayerNorm: one wave per (b,t) row, 4 rows/block ----------------
__global__ __launch_bounds__(256) void ln_kernel(const float* __restrict__ x,
    const float* __restrict__ w, const float* __restrict__ b, float* __restrict__ xn) {
  int row = blockIdx.x * 4 + (threadIdx.x >> 6);   // b*L + t   (4096 rows)
  int lane = threadIdx.x & 63;
  const float* xr = x + (size_t)row * HDIM;
  float4 v0 = ((const float4*)xr)[lane];
  float4 v1 = ((const float4*)xr)[lane + 64];
  float s  = v0.x + v0.y + v0.z + v0.w + v1.x + v1.y + v1.z + v1.w;
  float ss = v0.x*v0.x + v0.y*v0.y + v0.z*v0.z + v0.w*v0.w
           + v1.x*v1.x + v1.y*v1.y + v1.z*v1.z + v1.w*v1.w;
  #pragma unroll
  for (int m = 1; m < 64; m <<= 1) { s += __shfl_xor(s, m); ss += __shfl_xor(ss, m); }
  float mu   = s * (1.0f / HDIM);
  float var  = ss * (1.0f / HDIM) - mu * mu;
  float rstd = rsqrtf(var + 1e-5f);
  float4 w0 = ((const float4*)w)[lane];
  float4 w1 = ((const float4*)w)[lane + 64];
  float4 b0 = ((const float4*)b)[lane];
  float4 b1 = ((const float4*)b)[lane + 64];
  float4 o0, o1;
  o0.x = (v0.x - mu) * rstd * w0.x + b0.x;
  o0.y = (v0.y - mu) * rstd * w0.y + b0.y;
  o0.z = (v0.z - mu) * rstd * w0.z + b0.z;
  o0.w = (v0.w - mu) * rstd * w0.w + b0.w;
  o1.x = (v1.x - mu) * rstd * w1.x + b1.x;
  o1.y = (v1.y - mu) * rstd * w1.y + b1.y;
  o1.z = (v1.z - mu) * rstd * w1.z + b1.z;
  o1.w = (v1.w - mu) * rstd * w1.w + b1.w;
  float* xo = xn + (size_t)row * HDIM;
  ((float4*)xo)[lane] = o0;
  ((float4*)xo)[lane + 64] = o1;
}

// ---------------- K generation (register-resident DPLR column chains) ----------------
// K[32a+b] = Re( (c^T (Ab^32)^a) . (Ab^b Bb) )
__global__ __launch_bounds__(512) void kgen_kernel(
    const float* __restrict__ lre, const float* __restrict__ lim,
    const float* __restrict__ pre, const float* __restrict__ pim,
    const float* __restrict__ bre, const float* __restrict__ bim,
    const float* __restrict__ cre, const float* __restrict__ cim,
    const float* __restrict__ logstep, float* __restrict__ Kout) {
  __shared__ float2 Ldab[64], Lu[64], Lr[64], LBb[64];
  __shared__ float2 P[8][64];     // partial dots
  __shared__ float2 M32[4096];    // Ab^32 row-major [i][j]
  __shared__ float2 Rv[2048];     // [a*64+n] = (c^T (Ab^32)^a)[n]
  __shared__ float2 Wv[2048];     // [n*32+b] = (Ab^b Bb)[n]
  int tid = threadIdx.x;
  int j = tid & 63;       // column (phase B) / output index m (phase C)
  int p = tid >> 6;       // partial group: rows p*8..p*8+7

  // --- Phase A: DPLR setup (wave 0, lane n = mode n) ---
  if (tid < 64) {
    int n = tid;
    float step = expf(logstep[0]);
    float g = 2.0f / step;
    float lr = lre[n], li = lim[n];
    float pr = pre[n], pi = pim[n];
    float br = bre[n], bi = bim[n];
    float den  = (g - lr) * (g - lr) + li * li;
    float dinr = (g - lr) / den, dini = li / den;
    float dabr = (g + lr) * dinr - li * dini;
    float dabi = (g + lr) * dini + li * dinr;
    float ur = dinr * pr - dini * pi;
    float ui = dinr * pi + dini * pr;
    float qr = pr * dinr + pi * dini;
    float qi = pr * dini - pi * dinr;
    float pm2 = pr * pr + pi * pi;
    float betr = pm2 * dinr, beti = pm2 * dini;
    float gar = qr * br - qi * bi;
    float gai = qr * bi + qi * br;
    #pragma unroll
    for (int m = 1; m < 64; m <<= 1) {
      betr += __shfl_xor(betr, m); beti += __shfl_xor(beti, m);
      gar  += __shfl_xor(gar, m);  gai  += __shfl_xor(gai, m);
    }
    float obr = 1.0f + betr, obi = beti;
    float ob2 = obr * obr + obi * obi;
    float kr = -2.0f * g * obr / ob2;
    float ki =  2.0f * g * obi / ob2;
    float rr = kr * qr - ki * qi;
    float ri = kr * qi + ki * qr;
    float tgr = (gar * obr + gai * obi) / ob2;
    float tgi = (gai * obr - gar * obi) / ob2;
    float dbr = dinr * br - dini * bi;
    float dbi = dinr * bi + dini * br;
    float Bbr = 2.0f * (dbr - (ur * tgr - ui * tgi));
    float Bbi = 2.0f * (dbi - (ur * tgi + ui * tgr));
    float2 t;
    t.x = dabr; t.y = dabi; Ldab[n] = t;
    t.x = ur;   t.y = ui;   Lu[n]   = t;
    t.x = rr;   t.y = ri;   Lr[n]   = t;
    t.x = Bbr;  t.y = Bbi;  LBb[n]  = t;
  }
  __syncthreads();

  // --- Phase B: 64 column chains, 32 applications of Ab (DPLR form) ---
  float2 dab[8], u[8], rn[8], cv[8];
  #pragma unroll
  for (int ii = 0; ii < 8; ii++) {
    int n = p * 8 + ii;
    dab[ii] = Ldab[n]; u[ii] = Lu[n]; rn[ii] = Lr[n];
  }
  float2 rj = Lr[j];
  #pragma unroll
  for (int ii = 0; ii < 8; ii++) {
    int n = p * 8 + ii;
    cv[ii] = cmul(u[ii], rj);
    if (n == j) cv[ii] = cadd(cv[ii], dab[ii]);
  }
  for (int s = 0; s < 31; s++) {
    float2 part; part.x = 0.f; part.y = 0.f;
    #pragma unroll
    for (int ii = 0; ii < 8; ii++) part = cfma(rn[ii], cv[ii], part);
    P[p][j] = part;
    __syncthreads();
    float2 d; d.x = 0.f; d.y = 0.f;
    #pragma unroll
    for (int q = 0; q < 8; q++) d = cadd(d, P[q][j]);
    __syncthreads();
    #pragma unroll
    for (int ii = 0; ii < 8; ii++) {
      float2 nc = cmul(dab[ii], cv[ii]);
      nc = cfma(u[ii], d, nc);
      cv[ii] = nc;
    }
  }
  #pragma unroll
  for (int ii = 0; ii < 8; ii++) M32[(p * 8 + ii) * 64 + j] = cv[ii];
  if (tid < 64) { float2 cc; cc.x = cre[tid]; cc.y = cim[tid]; Rv[tid] = cc; }
  __syncthreads();

  // --- Phase C: R chain, parallel partials with register M-strip ---
  float2 Mreg[8];
  #pragma unroll
  for (int ii = 0; ii < 8; ii++) Mreg[ii] = M32[(p * 8 + ii) * 64 + j];
  for (int a = 1; a < 32; a++) {
    float2 part; part.x = 0.f; part.y = 0.f;
    #pragma unroll
    for (int ii = 0; ii < 8; ii++) {
      float2 Rk = Rv[(a - 1) * 64 + p * 8 + ii];
      part = cfma(Rk, Mreg[ii], part);
    }
    P[p][j] = part;
    __syncthreads();
    if (p == 0) {
      float2 d; d.x = 0.f; d.y = 0.f;
      #pragma unroll
      for (int q = 0; q < 8; q++) d = cadd(d, P[q][j]);
      Rv[a * 64 + j] = d;
    }
    __syncthreads();
  }

  // --- Phase D: W chain (wave 0) ---
  if (tid < 64) {
    int n = tid;
    float2 dab0 = Ldab[n], u0 = Lu[n], r0 = Lr[n];
    float2 w = LBb[n];
    Wv[n * 32 + 0] = w;
    for (int b = 1; b < 32; b++) {
      float dr = r0.x * w.x - r0.y * w.y;
      float di = r0.x * w.y + r0.y * w.x;
      #pragma unroll
      for (int m = 1; m < 64; m <<= 1) { dr += __shfl_xor(dr, m); di += __shfl_xor(di, m); }
      float2 nw;
      nw.x = dab0.x * w.x - dab0.y * w.y + u0.x * dr - u0.y * di;
      nw.y = dab0.x * w.y + dab0.y * w.x + u0.x * di + u0.y * dr;
      w = nw;
      Wv[n * 32 + b] = w;
    }
  }
  __syncthreads();

  // --- Phase E: K[32a+b] = Re(R_a . W_b) ---
  #pragma unroll
  for (int q = 0; q < 2; q++) {
    int midx = q * 512 + tid;
    int a = midx >> 5, b = midx & 31;
    float acc = 0.f;
    for (int n = 0; n < 64; n++) {
      float2 R = Rv[a * 64 + n];
      float2 W = Wv[n * 32 + b];
      acc += R.x * W.x - R.y * W.y;
    }
    Kout[midx] = acc;
  }
}

// ---------------- Prep: transpose(xn->U) + wconv + toeplitz, one launch ----------------
// blocks [0,512): transpose; [512,768): weight convert; [768,1280): toeplitz.
__global__ __launch_bounds__(256) void prep_kernel(
    const float* __restrict__ xn, const float* __restrict__ K,
    const float* __restrict__ w1, const float* __restrict__ w2,
    ushort* __restrict__ Uhi, ushort* __restrict__ Ulo,
    ushort* __restrict__ Thi, ushort* __restrict__ Tlo,
    ushort* __restrict__ Wst) {
  __shared__ float tile[64][65];
  int blk = blockIdx.x;
  int tid = threadIdx.x;
  if (blk < 512) {
    // --- transpose xn [B,L,H] -> U[c=b*512+h][t] hi/lo bf16 ---
    int ht = blk & 7, lt = (blk >> 3) & 15, b = blk >> 7;
    #pragma unroll
    for (int q = 0; q < 16; q++) {
      int idx = q * 256 + tid;
      int r = idx >> 6, c = idx & 63;               // r: l-offset, c: h-offset
      tile[r][c] = xn[((size_t)(b * LSEQ + lt * 64 + r)) * HDIM + ht * 64 + c];
    }
    __syncthreads();
    #pragma unroll
    for (int q = 0; q < 16; q++) {
      int idx = q * 256 + tid;
      int r = idx >> 6, c = idx & 63;               // r: h-offset, c: l-offset
      float v = tile[c][r];
      ushort h = f2bf(v);
      float rem = v - __bfloat162float(*(__hip_bfloat16*)&h);
      ushort l = f2bf(rem);
      size_t off = ((size_t)(b * HDIM + ht * 64 + r)) * LSEQ + lt * 64 + c;
      Uhi[off] = h;
      Ulo[off] = l;
    }
  } else if (blk < 768) {
    // --- weight convert: Wst[n][k], n<512 from w1, else w2 ---
    int e0 = ((blk - 512) * 256 + tid) * 8;         // 524288 total
    int n = e0 >> 9, k0 = e0 & 511;
    const float* Wr = (n < 512) ? (w1 + (size_t)n * 512 + k0)
                                : (w2 + (size_t)(n - 512) * 512 + k0);
    ushort tmp[8];
    #pragma unroll
    for (int t = 0; t < 8; t++) tmp[t] = f2bf(Wr[t]);
    *(short8*)&Wst[e0] = *(short8*)tmp;
  } else {
    // --- toeplitz: T[t][tau] = K[t-tau], hi/lo bf16 ---
    int r = blk - 768;                              // 0..511
    int t = r * 2 + (tid >> 7);
    int tau0 = (tid & 127) * 8;
    ushort hi[8], lo[8];
    #pragma unroll
    for (int q = 0; q < 8; q++) {
      int tau = tau0 + q;
      float v = (tau <= t) ? K[t - tau] : 0.f;
      hi[q] = f2bf(v);
      float rem = v - __bfloat162float(*(__hip_bfloat16*)&hi[q]);
      lo[q] = f2bf(rem);
    }
    *(short8*)&Thi[(size_t)t * 1024 + tau0] = *(short8*)hi;
    *(short8*)&Tlo[(size_t)t * 1024 + tau0] = *(short8*)lo;
  }
}

// -------- Conv GEMM: LDS-staged, triangular K-skip, balanced swizzle, GELU epilogue ----
// Y = Thi*Uhi^T + Tlo*Uhi^T + Thi*Ulo^T (within nonzero band); A = bf16(gelu(Y + d*xn))
__global__ __launch_bounds__(256) void conv_gemm_kernel(
    const ushort* __restrict__ Thi, const ushort* __restrict__ Tlo,
    const ushort* __restrict__ Uhi, const ushort* __restrict__ Ulo,
    const float* __restrict__ xn, const float* __restrict__ dptr,
    __hip_bfloat16* __restrict__ A) {
  __shared__ ushort sTh[64 * 40];
  __shared__ ushort sTl[64 * 40];
  __shared__ ushort sUh[64 * 40];
  __shared__ ushort sUl[64 * 40];
  int tid = threadIdx.x;
  int lane = tid & 63;
  int wv = tid >> 6;
  int wm = wv >> 1, wn = wv & 1;
  int by = blockIdx.y;                    // 0..15
  int bm = (by < 8) ? by : 23 - by;       // pair (by, by+8) -> (bm, 15-bm): balanced CU load
  int bn = blockIdx.x;                    // 0..31
  floatx4 acc[2][2] = {};
  int srow = tid >> 2;
  int scol = (tid & 3) * 8;
  int fr = lane & 15, fq = (lane >> 4) * 8;
  size_t Toff = (size_t)(bm * 64 + srow) * 1024 + scol;
  size_t Uoff = (size_t)(bn * 64 + srow) * 1024 + scol;
  int KT = 2 * (bm + 1);                  // k-tiles with any nonzero T (tau <= t)
  for (int kt = 0; kt < KT; kt++) {
    int k0 = kt * 32;
    *(uint4*)&sTh[srow * 40 + scol] = *(const uint4*)&Thi[Toff + k0];
    *(uint4*)&sTl[srow * 40 + scol] = *(const uint4*)&Tlo[Toff + k0];
    *(uint4*)&sUh[srow * 40 + scol] = *(const uint4*)&Uhi[Uoff + k0];
    *(uint4*)&sUl[srow * 40 + scol] = *(const uint4*)&Ulo[Uoff + k0];
    __syncthreads();
    short8 ah[2], al[2], bh[2], bl[2];
    #pragma unroll
    for (int i = 0; i < 2; i++) {
      ah[i] = *(const short8*)&sTh[(wm * 32 + i * 16 + fr) * 40 + fq];
      al[i] = *(const short8*)&sTl[(wm * 32 + i * 16 + fr) * 40 + fq];
      bh[i] = *(const short8*)&sUh[(wn * 32 + i * 16 + fr) * 40 + fq];
      bl[i] = *(const short8*)&sUl[(wn * 32 + i * 16 + fr) * 40 + fq];
    }
    #pragma unroll
    for (int i = 0; i < 2; i++)
      #pragma unroll
      for (int j = 0; j < 2; j++) {
        acc[i][j] = __builtin_amdgcn_mfma_f32_16x16x32_bf16(ah[i], bh[j], acc[i][j], 0, 0, 0);
        acc[i][j] = __builtin_amdgcn_mfma_f32_16x16x32_bf16(al[i], bh[j], acc[i][j], 0, 0, 0);
        acc[i][j] = __builtin_amdgcn_mfma_f32_16x16x32_bf16(ah[i], bl[j], acc[i][j], 0, 0, 0);
      }
    __syncthreads();
  }
  float d = dptr[0];
  int row0 = bm * 64 + wm * 32;
  int col0 = bn * 64 + wn * 32;
  int fc = lane & 15, frq = (lane >> 4) * 4;
  #pragma unroll
  for (int i = 0; i < 2; i++)
    #pragma unroll
    for (int j = 0; j < 2; j++)
      #pragma unroll
      for (int r = 0; r < 4; r++) {
        int t = row0 + i * 16 + frq + r;
        int c = col0 + j * 16 + fc;
        int b = c >> 9, h = c & 511;
        size_t off = (size_t)(b * LSEQ + t) * HDIM + h;
        float y = acc[i][j][r] + d * xn[off];
        float tnh = tanhf(0.7978845608028654f * (y + 0.044715f * y * y * y));
        A[off] = __float2bfloat16(0.5f * y * (1.0f + tnh));
      }
}

// ---- Proj GEMM: LDS-staged dual tile (C1,C2) + fused sigmoid-gate epilogue ----
// out[bt,n] = x[bt,n] + (A.W1^T + ob)[bt,n] * sigmoid((A.W2^T + o2b)[bt,n])
__global__ __launch_bounds__(256) void proj_kernel(
    const __hip_bfloat16* __restrict__ Abuf, const ushort* __restrict__ Wst,
    const float* __restrict__ x, const float* __restrict__ ob,
    const float* __restrict__ o2b, float* __restrict__ out) {
  __shared__ ushort sA[64 * 40];
  __shared__ ushort sW1[64 * 40];
  __shared__ ushort sW2[64 * 40];
  int tid = threadIdx.x;
  int lane = tid & 63;
  int wv = tid >> 6;
  int wm = wv >> 1, wn = wv & 1;
  int bm = blockIdx.y, bn = blockIdx.x;   // bm<64 (bt tiles), bn<8 (n tiles)
  int srow = tid >> 2;
  int scol = (tid & 3) * 8;
  int fr = lane & 15, fq = (lane >> 4) * 8;
  floatx4 acc1[2][2] = {}, acc2[2][2] = {};
  const ushort* Ab = (const ushort*)Abuf;
  size_t Aoff  = (size_t)(bm * 64 + srow) * 512 + scol;
  size_t W1off = (size_t)(bn * 64 + srow) * 512 + scol;
  size_t W2off = W1off + (size_t)512 * 512;
  for (int kt = 0; kt < 16; kt++) {
    int k0 = kt * 32;
    *(uint4*)&sA[srow * 40 + scol]  = *(const uint4*)&Ab[Aoff + k0];
    *(uint4*)&sW1[srow * 40 + scol] = *(const uint4*)&Wst[W1off + k0];
    *(uint4*)&sW2[srow * 40 + scol] = *(const uint4*)&Wst[W2off + k0];
    __syncthreads();
    short8 af[2], b1[2], b2[2];
    #pragma unroll
    for (int i = 0; i < 2; i++) {
      af[i] = *(const short8*)&sA[(wm * 32 + i * 16 + fr) * 40 + fq];
      b1[i] = *(const short8*)&sW1[(wn * 32 + i * 16 + fr) * 40 + fq];
      b2[i] = *(const short8*)&sW2[(wn * 32 + i * 16 + fr) * 40 + fq];
    }
    #pragma unroll
    for (int i = 0; i < 2; i++)
      #pragma unroll
      for (int j = 0; j < 2; j++) {
        acc1[i][j] = __builtin_amdgcn_mfma_f32_16x16x32_bf16(af[i], b1[j], acc1[i][j], 0, 0, 0);
        acc2[i][j] = __builtin_amdgcn_mfma_f32_16x16x32_bf16(af[i], b2[j], acc2[i][j], 0, 0, 0);
      }
    __syncthreads();
  }
  int row0 = bm * 64 + wm * 32;
  int col0 = bn * 64 + wn * 32;
  int fc = lane & 15, frq = (lane >> 4) * 4;
  #pragma unroll
  for (int i = 0; i < 2; i++)
    #pragma unroll
    for (int j = 0; j < 2; j++)
      #pragma unroll
      for (int r = 0; r < 4; r++) {
        int row = row0 + i * 16 + frq + r;      // bt
        int col = col0 + j * 16 + fc;           // n in [0,512)
        float c1 = acc1[i][j][r] + ob[col];
        float c2 = acc2[i][j][r] + o2b[col];
        float gate = 1.0f / (1.0f + expf(-c2));
        size_t off = (size_t)row * HDIM + col;
        out[off] = x[off] + c1 * gate;
      }
}

extern "C" void kernel_launch(void* const* d_in, const int* in_sizes, int n_in,
                              void* d_out, int out_size, void* d_ws, size_t ws_size,
                              hipStream_t stream) {
  const float* x   = (const float*)d_in[0];
  const float* nw  = (const float*)d_in[1];
  const float* nb  = (const float*)d_in[2];
  const float* lre = (const float*)d_in[3];
  const float* lim = (const float*)d_in[4];
  const float* pre = (const float*)d_in[5];
  const float* pim = (const float*)d_in[6];
  const float* bre = (const float*)d_in[7];
  const float* bim = (const float*)d_in[8];
  const float* cre = (const float*)d_in[9];
  const float* cim = (const float*)d_in[10];
  const float* dsc = (const float*)d_in[11];
  const float* lst = (const float*)d_in[12];
  const float* w1  = (const float*)d_in[13];
  const float* ob  = (const float*)d_in[14];
  const float* w2  = (const float*)d_in[15];
  const float* o2b = (const float*)d_in[16];

  char* ws = (char*)d_ws;
  // Workspace layout (26 MB used, no aliasing):
  float* xn    = (float*)(ws);                          // 0..8MB
  ushort* Uhi  = (ushort*)(ws + (size_t)(8  << 20));    // 8..12MB
  ushort* Ulo  = (ushort*)(ws + (size_t)(12 << 20));    // 12..16MB
  ushort* Thi  = (ushort*)(ws + (size_t)(16 << 20));    // 16..18MB
  ushort* Tlo  = (ushort*)(ws + (size_t)(18 << 20));    // 18..20MB
  ushort* Wst  = (ushort*)(ws + (size_t)(20 << 20));    // 20..21MB
  __hip_bfloat16* Abuf = (__hip_bfloat16*)(ws + (size_t)(21 << 20)); // 21..25MB
  float* Kbuf  = (float*)(ws + (size_t)(25 << 20));     // 4KB
  float* out   = (float*)d_out;

  ln_kernel<<<dim3(1024), dim3(256), 0, stream>>>(x, nw, nb, xn);
  kgen_kernel<<<dim3(1), dim3(512), 0, stream>>>(lre, lim, pre, pim, bre, bim,
                                                 cre, cim, lst, Kbuf);
  prep_kernel<<<dim3(1280), dim3(256), 0, stream>>>(xn, Kbuf, w1, w2,
                                                    Uhi, Ulo, Thi, Tlo, Wst);
  conv_gemm_kernel<<<dim3(32, 16), dim3(256), 0, stream>>>(Thi, Tlo, Uhi, Ulo,
                                                           xn, dsc, Abuf);
  proj_kernel<<<dim3(8, 64), dim3(256), 0, stream>>>(Abuf, Wst, x, ob, o2b, out);
}

// Round 8
// 172.126 us; speedup vs baseline: 1.3427x; 1.0664x over previous
//
#include <hip/hip_runtime.h>
#include <hip/hip_bf16.h>
#include <math.h>

#define HDIM 512
#define LSEQ 1024
#define BSZ  4

typedef __attribute__((ext_vector_type(8))) short short8;
typedef __attribute__((ext_vector_type(4))) float floatx4;

__device__ __forceinline__ float2 cmul(float2 a, float2 b) {
  float2 r;
  r.x = a.x * b.x - a.y * b.y;
  r.y = a.x * b.y + a.y * b.x;
  return r;
}
__device__ __forceinline__ float2 cadd(float2 a, float2 b) {
  float2 r; r.x = a.x + b.x; r.y = a.y + b.y; return r;
}
__device__ __forceinline__ float2 cfma(float2 a, float2 b, float2 c) {
  c.x += a.x * b.x - a.y * b.y;
  c.y += a.x * b.y + a.y * b.x;
  return c;
}
__device__ __forceinline__ ushort f2bf(float f) {
  __hip_bfloat16 h = __float2bfloat16(f);
  return *(ushort*)&h;
}

// ============ Stage 1: block 0 = K generation; blocks 1..456 = LayerNorm ============
// kgen: K[32a+b] = Re( (c^T (Ab^32)^a) . (Ab^b Bb) )
//  - Phase B: 64 DPLR column chains, one per 8-lane group, register-resident, NO barriers
//  - Phase D (wave 8, concurrent with B): W chain via 64-lane butterfly
//  - Phase C: R chain, M32 strip stays in registers from Phase B; 1 barrier/step
__global__ __launch_bounds__(576) void stage1_kernel(
    const float* __restrict__ x, const float* __restrict__ nw,
    const float* __restrict__ nb, float* __restrict__ xn,
    const float* __restrict__ lre, const float* __restrict__ lim,
    const float* __restrict__ pre, const float* __restrict__ pim,
    const float* __restrict__ bre, const float* __restrict__ bim,
    const float* __restrict__ cre, const float* __restrict__ cim,
    const float* __restrict__ logstep, float* __restrict__ Kout) {
  __shared__ float2 Ldab[64], Lu[64], Lr[64], LBb[64];
  __shared__ float2 Rv[2048];     // [a*64+n] = (c^T (Ab^32)^a)[n]
  __shared__ float2 Wv[2048];     // [n*32+b] = (Ab^b Bb)[n]
  int tid = threadIdx.x;
  int wv = tid >> 6;              // wave 0..8
  int lane = tid & 63;

  if (blockIdx.x != 0) {
    // ---------------- LayerNorm: 9 rows per block, one wave per row ----------------
    int row = (blockIdx.x - 1) * 9 + wv;
    if (row >= BSZ * LSEQ) return;
    const float* xr = x + (size_t)row * HDIM;
    float4 v0 = ((const float4*)xr)[lane];
    float4 v1 = ((const float4*)xr)[lane + 64];
    float s  = v0.x + v0.y + v0.z + v0.w + v1.x + v1.y + v1.z + v1.w;
    float ss = v0.x*v0.x + v0.y*v0.y + v0.z*v0.z + v0.w*v0.w
             + v1.x*v1.x + v1.y*v1.y + v1.z*v1.z + v1.w*v1.w;
    #pragma unroll
    for (int m = 1; m < 64; m <<= 1) { s += __shfl_xor(s, m); ss += __shfl_xor(ss, m); }
    float mu   = s * (1.0f / HDIM);
    float var  = ss * (1.0f / HDIM) - mu * mu;
    float rstd = rsqrtf(var + 1e-5f);
    float4 w0 = ((const float4*)nw)[lane];
    float4 w1 = ((const float4*)nw)[lane + 64];
    float4 b0 = ((const float4*)nb)[lane];
    float4 b1 = ((const float4*)nb)[lane + 64];
    float4 o0, o1;
    o0.x = (v0.x - mu) * rstd * w0.x + b0.x;
    o0.y = (v0.y - mu) * rstd * w0.y + b0.y;
    o0.z = (v0.z - mu) * rstd * w0.z + b0.z;
    o0.w = (v0.w - mu) * rstd * w0.w + b0.w;
    o1.x = (v1.x - mu) * rstd * w1.x + b1.x;
    o1.y = (v1.y - mu) * rstd * w1.y + b1.y;
    o1.z = (v1.z - mu) * rstd * w1.z + b1.z;
    o1.w = (v1.w - mu) * rstd * w1.w + b1.w;
    float* xo = xn + (size_t)row * HDIM;
    ((float4*)xo)[lane] = o0;
    ((float4*)xo)[lane + 64] = o1;
    return;
  }

  // ================= block 0: K generation =================
  // --- Phase A: DPLR setup (wave 0); wave 8 inits Rv[0] = c ---
  if (tid < 64) {
    int n = tid;
    float step = expf(logstep[0]);
    float g = 2.0f / step;
    float lr = lre[n], li = lim[n];
    float pr = pre[n], pi = pim[n];
    float br = bre[n], bi = bim[n];
    float den  = (g - lr) * (g - lr) + li * li;
    float dinr = (g - lr) / den, dini = li / den;
    float dabr = (g + lr) * dinr - li * dini;
    float dabi = (g + lr) * dini + li * dinr;
    float ur = dinr * pr - dini * pi;
    float ui = dinr * pi + dini * pr;
    float qr = pr * dinr + pi * dini;
    float qi = pr * dini - pi * dinr;
    float pm2 = pr * pr + pi * pi;
    float betr = pm2 * dinr, beti = pm2 * dini;
    float gar = qr * br - qi * bi;
    float gai = qr * bi + qi * br;
    #pragma unroll
    for (int m = 1; m < 64; m <<= 1) {
      betr += __shfl_xor(betr, m); beti += __shfl_xor(beti, m);
      gar  += __shfl_xor(gar, m);  gai  += __shfl_xor(gai, m);
    }
    float obr = 1.0f + betr, obi = beti;
    float ob2 = obr * obr + obi * obi;
    float kr = -2.0f * g * obr / ob2;
    float ki =  2.0f * g * obi / ob2;
    float rr = kr * qr - ki * qi;
    float ri = kr * qi + ki * qr;
    float tgr = (gar * obr + gai * obi) / ob2;
    float tgi = (gai * obr - gar * obi) / ob2;
    float dbr = dinr * br - dini * bi;
    float dbi = dinr * bi + dini * br;
    float Bbr = 2.0f * (dbr - (ur * tgr - ui * tgi));
    float Bbi = 2.0f * (dbi - (ur * tgi + ui * tgr));
    float2 t;
    t.x = dabr; t.y = dabi; Ldab[n] = t;
    t.x = ur;   t.y = ui;   Lu[n]   = t;
    t.x = rr;   t.y = ri;   Lr[n]   = t;
    t.x = Bbr;  t.y = Bbi;  LBb[n]  = t;
  }
  if (wv == 8) { float2 cc; cc.x = cre[lane]; cc.y = cim[lane]; Rv[lane] = cc; }
  __syncthreads();

  int g8 = lane >> 3;             // group within wave (0..7)
  int q8 = lane & 7;              // lane within group: rows q8*8..q8*8+7
  int jm = wv * 8 + g8;           // column (B) / output m (C), valid for wv<8
  float2 cv[8];                   // column strip; becomes M32[k][jm] strip for C

  if (wv < 8) {
    // --- Phase B: barrier-free column chains, 32 applications of Ab ---
    float2 dab[8], u[8], rn[8];
    #pragma unroll
    for (int ii = 0; ii < 8; ii++) {
      int n = q8 * 8 + ii;
      dab[ii] = Ldab[n]; u[ii] = Lu[n]; rn[ii] = Lr[n];
    }
    float2 rj = Lr[jm];
    #pragma unroll
    for (int ii = 0; ii < 8; ii++) {
      int n = q8 * 8 + ii;
      cv[ii] = cmul(u[ii], rj);                     // Ab = u r^T + diag(dab)
      if (n == jm) cv[ii] = cadd(cv[ii], dab[ii]);  // application #1
    }
    for (int s = 0; s < 31; s++) {                  // applications #2..#32
      float2 part; part.x = 0.f; part.y = 0.f;
      #pragma unroll
      for (int ii = 0; ii < 8; ii++) part = cfma(rn[ii], cv[ii], part);
      #pragma unroll
      for (int m = 1; m < 8; m <<= 1) {
        part.x += __shfl_xor(part.x, m);
        part.y += __shfl_xor(part.y, m);
      }
      #pragma unroll
      for (int ii = 0; ii < 8; ii++) {
        float2 nc = cmul(dab[ii], cv[ii]);
        cv[ii] = cfma(u[ii], part, nc);
      }
    }
  } else {
    // --- Phase D (concurrent): W chain, 64-lane butterfly dots ---
    float2 dab0 = Ldab[lane], u0 = Lu[lane], r0 = Lr[lane];
    float2 w = LBb[lane];
    Wv[lane * 32 + 0] = w;
    for (int b = 1; b < 32; b++) {
      float dr = r0.x * w.x - r0.y * w.y;
      float di = r0.x * w.y + r0.y * w.x;
      #pragma unroll
      for (int m = 1; m < 64; m <<= 1) { dr += __shfl_xor(dr, m); di += __shfl_xor(di, m); }
      float2 nw2;
      nw2.x = dab0.x * w.x - dab0.y * w.y + u0.x * dr - u0.y * di;
      nw2.y = dab0.x * w.y + dab0.y * w.x + u0.x * di + u0.y * dr;
      w = nw2;
      Wv[lane * 32 + b] = w;
    }
  }
  __syncthreads();

  // --- Phase C: R chain, uniform 1 barrier/step; M strip = cv registers ---
  for (int a = 1; a < 32; a++) {
    if (wv < 8) {
      float2 part; part.x = 0.f; part.y = 0.f;
      #pragma unroll
      for (int ii = 0; ii < 8; ii++) {
        float2 Rk = Rv[(a - 1) * 64 + q8 * 8 + ii];   // 8-way broadcast read
        part = cfma(Rk, cv[ii], part);
      }
      #pragma unroll
      for (int m = 1; m < 8; m <<= 1) {
        part.x += __shfl_xor(part.x, m);
        part.y += __shfl_xor(part.y, m);
      }
      if (q8 == 0) Rv[a * 64 + jm] = part;
    }
    __syncthreads();
  }

  // --- Phase E: K[32a+b] = Re(R_a . W_b) ---
  for (int midx = tid; midx < 1024; midx += 576) {
    int a = midx >> 5, b = midx & 31;
    float acc = 0.f;
    for (int n = 0; n < 64; n++) {
      float2 R = Rv[a * 64 + n];
      float2 W = Wv[n * 32 + b];
      acc += R.x * W.x - R.y * W.y;
    }
    Kout[midx] = acc;
  }
}

// ---------------- Prep: transpose(xn->U) + wconv + toeplitz, one launch ----------------
// blocks [0,512): transpose; [512,768): weight convert; [768,1280): toeplitz.
__global__ __launch_bounds__(256) void prep_kernel(
    const float* __restrict__ xn, const float* __restrict__ K,
    const float* __restrict__ w1, const float* __restrict__ w2,
    ushort* __restrict__ Uhi, ushort* __restrict__ Ulo,
    ushort* __restrict__ Thi, ushort* __restrict__ Tlo,
    ushort* __restrict__ Wst) {
  __shared__ float tile[64][65];
  int blk = blockIdx.x;
  int tid = threadIdx.x;
  if (blk < 512) {
    // --- transpose xn [B,L,H] -> U[c=b*512+h][t] hi/lo bf16 ---
    int ht = blk & 7, lt = (blk >> 3) & 15, b = blk >> 7;
    #pragma unroll
    for (int q = 0; q < 16; q++) {
      int idx = q * 256 + tid;
      int r = idx >> 6, c = idx & 63;               // r: l-offset, c: h-offset
      tile[r][c] = xn[((size_t)(b * LSEQ + lt * 64 + r)) * HDIM + ht * 64 + c];
    }
    __syncthreads();
    #pragma unroll
    for (int q = 0; q < 16; q++) {
      int idx = q * 256 + tid;
      int r = idx >> 6, c = idx & 63;               // r: h-offset, c: l-offset
      float v = tile[c][r];
      ushort h = f2bf(v);
      float rem = v - __bfloat162float(*(__hip_bfloat16*)&h);
      ushort l = f2bf(rem);
      size_t off = ((size_t)(b * HDIM + ht * 64 + r)) * LSEQ + lt * 64 + c;
      Uhi[off] = h;
      Ulo[off] = l;
    }
  } else if (blk < 768) {
    // --- weight convert: Wst[n][k], n<512 from w1, else w2 ---
    int e0 = ((blk - 512) * 256 + tid) * 8;         // 524288 total
    int n = e0 >> 9, k0 = e0 & 511;
    const float* Wr = (n < 512) ? (w1 + (size_t)n * 512 + k0)
                                : (w2 + (size_t)(n - 512) * 512 + k0);
    ushort tmp[8];
    #pragma unroll
    for (int t = 0; t < 8; t++) tmp[t] = f2bf(Wr[t]);
    *(short8*)&Wst[e0] = *(short8*)tmp;
  } else {
    // --- toeplitz: T[t][tau] = K[t-tau], hi/lo bf16 ---
    int r = blk - 768;                              // 0..511
    int t = r * 2 + (tid >> 7);
    int tau0 = (tid & 127) * 8;
    ushort hi[8], lo[8];
    #pragma unroll
    for (int q = 0; q < 8; q++) {
      int tau = tau0 + q;
      float v = (tau <= t) ? K[t - tau] : 0.f;
      hi[q] = f2bf(v);
      float rem = v - __bfloat162float(*(__hip_bfloat16*)&hi[q]);
      lo[q] = f2bf(rem);
    }
    *(short8*)&Thi[(size_t)t * 1024 + tau0] = *(short8*)hi;
    *(short8*)&Tlo[(size_t)t * 1024 + tau0] = *(short8*)lo;
  }
}

// -------- Conv GEMM: LDS-staged, triangular K-skip, balanced swizzle, GELU epilogue ----
// Y = Thi*Uhi^T + Tlo*Uhi^T + Thi*Ulo^T (within nonzero band); A = bf16(gelu(Y + d*xn))
__global__ __launch_bounds__(256) void conv_gemm_kernel(
    const ushort* __restrict__ Thi, const ushort* __restrict__ Tlo,
    const ushort* __restrict__ Uhi, const ushort* __restrict__ Ulo,
    const float* __restrict__ xn, const float* __restrict__ dptr,
    __hip_bfloat16* __restrict__ A) {
  __shared__ ushort sTh[64 * 40];
  __shared__ ushort sTl[64 * 40];
  __shared__ ushort sUh[64 * 40];
  __shared__ ushort sUl[64 * 40];
  int tid = threadIdx.x;
  int lane = tid & 63;
  int wv = tid >> 6;
  int wm = wv >> 1, wn = wv & 1;
  int by = blockIdx.y;                    // 0..15
  int bm = (by < 8) ? by : 23 - by;       // pair (by, by+8) -> (bm, 15-bm): balanced CU load
  int bn = blockIdx.x;                    // 0..31
  floatx4 acc[2][2] = {};
  int srow = tid >> 2;
  int scol = (tid & 3) * 8;
  int fr = lane & 15, fq = (lane >> 4) * 8;
  size_t Toff = (size_t)(bm * 64 + srow) * 1024 + scol;
  size_t Uoff = (size_t)(bn * 64 + srow) * 1024 + scol;
  int KT = 2 * (bm + 1);                  // k-tiles with any nonzero T (tau <= t)
  for (int kt = 0; kt < KT; kt++) {
    int k0 = kt * 32;
    *(uint4*)&sTh[srow * 40 + scol] = *(const uint4*)&Thi[Toff + k0];
    *(uint4*)&sTl[srow * 40 + scol] = *(const uint4*)&Tlo[Toff + k0];
    *(uint4*)&sUh[srow * 40 + scol] = *(const uint4*)&Uhi[Uoff + k0];
    *(uint4*)&sUl[srow * 40 + scol] = *(const uint4*)&Ulo[Uoff + k0];
    __syncthreads();
    short8 ah[2], al[2], bh[2], bl[2];
    #pragma unroll
    for (int i = 0; i < 2; i++) {
      ah[i] = *(const short8*)&sTh[(wm * 32 + i * 16 + fr) * 40 + fq];
      al[i] = *(const short8*)&sTl[(wm * 32 + i * 16 + fr) * 40 + fq];
      bh[i] = *(const short8*)&sUh[(wn * 32 + i * 16 + fr) * 40 + fq];
      bl[i] = *(const short8*)&sUl[(wn * 32 + i * 16 + fr) * 40 + fq];
    }
    #pragma unroll
    for (int i = 0; i < 2; i++)
      #pragma unroll
      for (int j = 0; j < 2; j++) {
        acc[i][j] = __builtin_amdgcn_mfma_f32_16x16x32_bf16(ah[i], bh[j], acc[i][j], 0, 0, 0);
        acc[i][j] = __builtin_amdgcn_mfma_f32_16x16x32_bf16(al[i], bh[j], acc[i][j], 0, 0, 0);
        acc[i][j] = __builtin_amdgcn_mfma_f32_16x16x32_bf16(ah[i], bl[j], acc[i][j], 0, 0, 0);
      }
    __syncthreads();
  }
  float d = dptr[0];
  int row0 = bm * 64 + wm * 32;
  int col0 = bn * 64 + wn * 32;
  int fc = lane & 15, frq = (lane >> 4) * 4;
  #pragma unroll
  for (int i = 0; i < 2; i++)
    #pragma unroll
    for (int j = 0; j < 2; j++)
      #pragma unroll
      for (int r = 0; r < 4; r++) {
        int t = row0 + i * 16 + frq + r;
        int c = col0 + j * 16 + fc;
        int b = c >> 9, h = c & 511;
        size_t off = (size_t)(b * LSEQ + t) * HDIM + h;
        float y = acc[i][j][r] + d * xn[off];
        float tnh = tanhf(0.7978845608028654f * (y + 0.044715f * y * y * y));
        A[off] = __float2bfloat16(0.5f * y * (1.0f + tnh));
      }
}

// ---- Proj GEMM: LDS-staged dual tile (C1,C2) + fused sigmoid-gate epilogue ----
// out[bt,n] = x[bt,n] + (A.W1^T + ob)[bt,n] * sigmoid((A.W2^T + o2b)[bt,n])
__global__ __launch_bounds__(256) void proj_kernel(
    const __hip_bfloat16* __restrict__ Abuf, const ushort* __restrict__ Wst,
    const float* __restrict__ x, const float* __restrict__ ob,
    const float* __restrict__ o2b, float* __restrict__ out) {
  __shared__ ushort sA[64 * 40];
  __shared__ ushort sW1[64 * 40];
  __shared__ ushort sW2[64 * 40];
  int tid = threadIdx.x;
  int lane = tid & 63;
  int wv = tid >> 6;
  int wm = wv >> 1, wn = wv & 1;
  int bm = blockIdx.y, bn = blockIdx.x;   // bm<64 (bt tiles), bn<8 (n tiles)
  int srow = tid >> 2;
  int scol = (tid & 3) * 8;
  int fr = lane & 15, fq = (lane >> 4) * 8;
  floatx4 acc1[2][2] = {}, acc2[2][2] = {};
  const ushort* Ab = (const ushort*)Abuf;
  size_t Aoff  = (size_t)(bm * 64 + srow) * 512 + scol;
  size_t W1off = (size_t)(bn * 64 + srow) * 512 + scol;
  size_t W2off = W1off + (size_t)512 * 512;
  for (int kt = 0; kt < 16; kt++) {
    int k0 = kt * 32;
    *(uint4*)&sA[srow * 40 + scol]  = *(const uint4*)&Ab[Aoff + k0];
    *(uint4*)&sW1[srow * 40 + scol] = *(const uint4*)&Wst[W1off + k0];
    *(uint4*)&sW2[srow * 40 + scol] = *(const uint4*)&Wst[W2off + k0];
    __syncthreads();
    short8 af[2], b1[2], b2[2];
    #pragma unroll
    for (int i = 0; i < 2; i++) {
      af[i] = *(const short8*)&sA[(wm * 32 + i * 16 + fr) * 40 + fq];
      b1[i] = *(const short8*)&sW1[(wn * 32 + i * 16 + fr) * 40 + fq];
      b2[i] = *(const short8*)&sW2[(wn * 32 + i * 16 + fr) * 40 + fq];
    }
    #pragma unroll
    for (int i = 0; i < 2; i++)
      #pragma unroll
      for (int j = 0; j < 2; j++) {
        acc1[i][j] = __builtin_amdgcn_mfma_f32_16x16x32_bf16(af[i], b1[j], acc1[i][j], 0, 0, 0);
        acc2[i][j] = __builtin_amdgcn_mfma_f32_16x16x32_bf16(af[i], b2[j], acc2[i][j], 0, 0, 0);
      }
    __syncthreads();
  }
  int row0 = bm * 64 + wm * 32;
  int col0 = bn * 64 + wn * 32;
  int fc = lane & 15, frq = (lane >> 4) * 4;
  #pragma unroll
  for (int i = 0; i < 2; i++)
    #pragma unroll
    for (int j = 0; j < 2; j++)
      #pragma unroll
      for (int r = 0; r < 4; r++) {
        int row = row0 + i * 16 + frq + r;      // bt
        int col = col0 + j * 16 + fc;           // n in [0,512)
        float c1 = acc1[i][j][r] + ob[col];
        float c2 = acc2[i][j][r] + o2b[col];
        float gate = 1.0f / (1.0f + expf(-c2));
        size_t off = (size_t)row * HDIM + col;
        out[off] = x[off] + c1 * gate;
      }
}

extern "C" void kernel_launch(void* const* d_in, const int* in_sizes, int n_in,
                              void* d_out, int out_size, void* d_ws, size_t ws_size,
                              hipStream_t stream) {
  const float* x   = (const float*)d_in[0];
  const float* nw  = (const float*)d_in[1];
  const float* nb  = (const float*)d_in[2];
  const float* lre = (const float*)d_in[3];
  const float* lim = (const float*)d_in[4];
  const float* pre = (const float*)d_in[5];
  const float* pim = (const float*)d_in[6];
  const float* bre = (const float*)d_in[7];
  const float* bim = (const float*)d_in[8];
  const float* cre = (const float*)d_in[9];
  const float* cim = (const float*)d_in[10];
  const float* dsc = (const float*)d_in[11];
  const float* lst = (const float*)d_in[12];
  const float* w1  = (const float*)d_in[13];
  const float* ob  = (const float*)d_in[14];
  const float* w2  = (const float*)d_in[15];
  const float* o2b = (const float*)d_in[16];

  char* ws = (char*)d_ws;
  // Workspace layout (26 MB used, no aliasing):
  float* xn    = (float*)(ws);                          // 0..8MB
  ushort* Uhi  = (ushort*)(ws + (size_t)(8  << 20));    // 8..12MB
  ushort* Ulo  = (ushort*)(ws + (size_t)(12 << 20));    // 12..16MB
  ushort* Thi  = (ushort*)(ws + (size_t)(16 << 20));    // 16..18MB
  ushort* Tlo  = (ushort*)(ws + (size_t)(18 << 20));    // 18..20MB
  ushort* Wst  = (ushort*)(ws + (size_t)(20 << 20));    // 20..21MB
  __hip_bfloat16* Abuf = (__hip_bfloat16*)(ws + (size_t)(21 << 20)); // 21..25MB
  float* Kbuf  = (float*)(ws + (size_t)(25 << 20));     // 4KB
  float* out   = (float*)d_out;

  stage1_kernel<<<dim3(457), dim3(576), 0, stream>>>(x, nw, nb, xn,
                                                     lre, lim, pre, pim, bre, bim,
                                                     cre, cim, lst, Kbuf);
  prep_kernel<<<dim3(1280), dim3(256), 0, stream>>>(xn, Kbuf, w1, w2,
                                                    Uhi, Ulo, Thi, Tlo, Wst);
  conv_gemm_kernel<<<dim3(32, 16), dim3(256), 0, stream>>>(Thi, Tlo, Uhi, Ulo,
                                                           xn, dsc, Abuf);
  proj_kernel<<<dim3(8, 64), dim3(256), 0, stream>>>(Abuf, Wst, x, ob, o2b, out);
}